// Round 3
// baseline (4252.116 us; speedup 1.0000x reference)
//
#include <hip/hip_runtime.h>
#include <hip/hip_bf16.h>
#include <cstdint>

#define VOCAB 28996
#define T_STEPS 1024
#define D_IN 256
#define HDIM 512

using f32x4 = __attribute__((ext_vector_type(4))) float;
using s16x8 = __attribute__((ext_vector_type(8))) short;

static __device__ __forceinline__ unsigned short f2bf(float f){
    unsigned u = __float_as_uint(f);
    u = u + 0x7FFFu + ((u >> 16) & 1u);   // round-to-nearest-even
    return (unsigned short)(u >> 16);
}

#define SENT_U 0x7FC00001u

// ---------------------------------------------------------------------------
// Kernel 1: init hs buffer (row 0 = h0, rows 1..1024 = NaN sentinel) + ctrl
// ---------------------------------------------------------------------------
__global__ void init_hs_kernel(const float* __restrict__ h0, float* __restrict__ hs,
                               unsigned* __restrict__ ctrl){
    const int col = threadIdx.x;          // 0..511
    const int row = blockIdx.x;           // 0..1024
    float v = (row == 0) ? h0[col] : __uint_as_float(SENT_U);
    hs[(size_t)row * HDIM + col] = v;
    if (row == 0 && col < 8) ctrl[col] = 0u;
}

// ---------------------------------------------------------------------------
// Kernel 2: xg = x @ w_ih^T + b_ih   ([1024 x 256] @ [256 -> 1536])  fp32
// ---------------------------------------------------------------------------
__global__ void xg_kernel(const float* __restrict__ x, const float* __restrict__ w_ih,
                          const float* __restrict__ b_ih, float* __restrict__ xg){
    __shared__ float xs[8][D_IN];
    const int tid = threadIdx.x;
    const int i   = blockIdx.x * 256 + tid;   // 0..1535
    const int t0  = blockIdx.y * 8;
    #pragma unroll
    for (int r = 0; r < 8; ++r)
        xs[r][tid] = x[(size_t)(t0 + r) * D_IN + tid];
    __syncthreads();

    float acc[8] = {0.f,0.f,0.f,0.f,0.f,0.f,0.f,0.f};
    const float* wrow = w_ih + (size_t)i * D_IN;
    for (int d = 0; d < D_IN; d += 4){
        float4 w4 = *(const float4*)(wrow + d);
        #pragma unroll
        for (int r = 0; r < 8; ++r){
            acc[r] += w4.x * xs[r][d]   + w4.y * xs[r][d+1]
                    + w4.z * xs[r][d+2] + w4.w * xs[r][d+3];
        }
    }
    const float b = b_ih[i];
    #pragma unroll
    for (int r = 0; r < 8; ++r)
        xg[(size_t)(t0 + r) * (3*HDIM) + i] = acc[r] + b;
}

// ---------------------------------------------------------------------------
// Kernel 3: sequential GRU scan — redundant per-XCD clusters, L2-atomic sync.
//
// Every XCD independently runs a 32-WG cluster on the SHARED hs buffer:
//  * rank claim: one non-blocking agent-scope fetch_add (no spin, no CAS).
//  * pollers read h_t via 64-bit atomic-add-of-opaque-zero (RMW executes at
//    the XCD's L2 -> always fresh, immune to L1 staleness, no MALL hop).
//  * writers publish via 32-bit atomic swap (lands in the same L2).
//  * clusters on different XCDs compute bit-identical values -> their dirty
//    L2 copies of hs collide benignly at writeback.
//  * a cluster missing members (uneven dispatch) times out (~225us bound,
//    block-consensus exit) after writing only correct values; pigeonhole
//    guarantees >=1 XCD hosts a complete 32-WG cluster that finishes hs.
// ---------------------------------------------------------------------------
__launch_bounds__(256, 1)
__global__ void scan_kernel(const float* __restrict__ xg, const float* __restrict__ w_hh,
                            const float* __restrict__ b_hh, float* hs, unsigned* ctrl){
    __shared__ float lds_pool[16000];   // ~62.5 KB occupancy limiter: <=2 WG/CU
    float* hbuf = lds_pool;             // first 512 floats = h row buffer
    __shared__ int blk_alive;
    __shared__ unsigned sh_rank;

    const int tid = threadIdx.x;
    if (tid == 0){
        unsigned xcc;
        asm volatile("s_getreg_b32 %0, hwreg(HW_REG_XCC_ID)" : "=s"(xcc));
        sh_rank = __hip_atomic_fetch_add(&ctrl[xcc & 7u], 1u, __ATOMIC_RELAXED,
                                         __HIP_MEMORY_SCOPE_AGENT);
        blk_alive = 1;
    }
    __syncthreads();
    const unsigned rank = sh_rank;
    if (rank >= 32u) return;            // uniform per WG

    const int c  = tid & 15;            // column-chunk selector
    const int jl = tid >> 4;            // 0..15
    const int j  = (int)rank * 16 + jl; // 0..511

    // -- recurrent weights -> registers (96 VGPRs) --
    float4 WR[8], WZ[8], WN[8];
    const float* wr = w_hh + (size_t)j * HDIM;
    const float* wz = w_hh + (size_t)(HDIM   + j) * HDIM;
    const float* wn = w_hh + (size_t)(2*HDIM + j) * HDIM;
    #pragma unroll
    for (int s = 0; s < 8; ++s){
        const int off = 4 * (c + 16 * s);
        WR[s] = *(const float4*)(wr + off);
        WZ[s] = *(const float4*)(wz + off);
        WN[s] = *(const float4*)(wn + off);
    }
    float bhr = 0.f, bhz = 0.f, bhn = 0.f;
    if (c == 0){ bhr = b_hh[j]; bhz = b_hh[HDIM + j]; bhn = b_hh[2*HDIM + j]; }

    // opaque zero: prevents InstCombine folding fetch_add(p,0) -> atomic load
    unsigned long long zero64 = 0ull;
    asm volatile("" : "+v"(zero64));

    // xg software pipeline (distance 1)
    float xr_c = 0.f, xz_c = 0.f, xn_c = 0.f;
    if (c == 0){ xr_c = xg[j]; xz_c = xg[HDIM + j]; xn_c = xg[2*HDIM + j]; }

    #pragma unroll 1
    for (int t = 0; t < T_STEPS; ++t){
        // prefetch next step's xg (latency hides under the poll)
        float xr_n = 0.f, xz_n = 0.f, xn_n = 0.f;
        if (c == 0 && t + 1 < T_STEPS){
            const float* xgn = xg + (size_t)(t + 1) * (3*HDIM);
            xr_n = xgn[j]; xz_n = xgn[HDIM + j]; xn_n = xgn[2*HDIM + j];
        }

        // ---- poll h_t (2 floats/thread) via L2 atomic RMW, bounded ----
        unsigned long long* src = (unsigned long long*)(hs + (size_t)t * HDIM + 2 * tid);
        unsigned long long vv;
        int spins = 0;
        for (;;){
            vv = __hip_atomic_fetch_add(src, zero64, __ATOMIC_RELAXED,
                                        __HIP_MEMORY_SCOPE_WORKGROUP);
            if ((unsigned)vv != SENT_U && (unsigned)(vv >> 32) != SENT_U) break;
            if (++spins > 1500){ blk_alive = 0; break; }   // incomplete cluster
        }
        hbuf[2*tid]     = __uint_as_float((unsigned)vv);
        hbuf[2*tid + 1] = __uint_as_float((unsigned)(vv >> 32));
        __syncthreads();
        if (!blk_alive) return;         // uniform consensus exit (no deadlock)

        // ---- partial matvec: 96 FMAs/lane, 6 independent chains ----
        float ar0=0.f, ar1=0.f, az0=0.f, az1=0.f, an0=0.f, an1=0.f;
        #pragma unroll
        for (int s = 0; s < 8; s += 2){
            float4 h4 = *(const float4*)&hbuf[4 * (c + 16 * s)];
            ar0 += WR[s].x*h4.x + WR[s].y*h4.y + WR[s].z*h4.z + WR[s].w*h4.w;
            az0 += WZ[s].x*h4.x + WZ[s].y*h4.y + WZ[s].z*h4.z + WZ[s].w*h4.w;
            an0 += WN[s].x*h4.x + WN[s].y*h4.y + WN[s].z*h4.z + WN[s].w*h4.w;
            float4 h5 = *(const float4*)&hbuf[4 * (c + 16 * (s+1))];
            ar1 += WR[s+1].x*h5.x + WR[s+1].y*h5.y + WR[s+1].z*h5.z + WR[s+1].w*h5.w;
            az1 += WZ[s+1].x*h5.x + WZ[s+1].y*h5.y + WZ[s+1].z*h5.z + WZ[s+1].w*h5.w;
            an1 += WN[s+1].x*h5.x + WN[s+1].y*h5.y + WN[s+1].z*h5.z + WN[s+1].w*h5.w;
        }
        float ar = ar0 + ar1, az = az0 + az1, an = an0 + an1;
        #pragma unroll
        for (int m = 1; m < 16; m <<= 1){
            ar += __shfl_xor(ar, m);
            az += __shfl_xor(az, m);
            an += __shfl_xor(an, m);
        }

        if (c == 0){
            const float r  = 1.0f / (1.0f + __expf(-(xr_c + ar + bhr)));
            const float z  = 1.0f / (1.0f + __expf(-(xz_c + az + bhz)));
            const float nn = xn_c + r * (an + bhn);
            const float e  = __expf(2.0f * nn);
            const float th = 1.0f - 2.0f / (e + 1.0f);   // tanh, inf-safe
            const float hnew = (1.0f - z) * th + z * hbuf[j];
            // publish via atomic swap -> guaranteed to land in this XCD's L2
            __hip_atomic_exchange((unsigned*)(hs + (size_t)(t + 1) * HDIM + j),
                                  __float_as_uint(hnew), __ATOMIC_RELAXED,
                                  __HIP_MEMORY_SCOPE_WORKGROUP);
        }
        xr_c = xr_n; xz_c = xz_n; xn_c = xn_n;
        __syncthreads();                // protect hbuf before next overwrite
    }
}

// ---------------------------------------------------------------------------
// Kernel 4: preds = hs[1..1024] @ w_pred^T + b_pred  (bf16 MFMA, fp32 out)
// ---------------------------------------------------------------------------
__launch_bounds__(256)
__global__ void pred_gemm_kernel(const float* __restrict__ hs, const float* __restrict__ w_pred,
                                 const float* __restrict__ b_pred, float* __restrict__ out){
    __shared__ unsigned short As[128 * 32];
    __shared__ unsigned short Bs[128 * 32];
    const int tid   = threadIdx.x;
    const int mtile = blockIdx.x;    // 0..7
    const int ntile = blockIdx.y;    // 0..226
    const int row  = tid >> 1, half = tid & 1;
    const int wave = tid >> 6, lane = tid & 63;
    const int wm = wave >> 1, wn = wave & 1;
    const int lr = lane & 15, kq = lane >> 4;

    f32x4 acc[4][4] = {};

    const float* Abase = hs + HDIM /*skip h0 row*/ + (size_t)(mtile * 128 + row) * HDIM;
    const int    nrow  = ntile * 128 + row;
    const float* Bbase = w_pred + (size_t)nrow * HDIM;

    for (int k0 = 0; k0 < HDIM; k0 += 32){
        {
            const float* srcp = Abase + k0 + half * 16;
            unsigned short* dst = &As[row * 32 + half * 16];
            #pragma unroll
            for (int q = 0; q < 4; ++q){
                float4 v = *(const float4*)(srcp + 4 * q);
                uint2 p;
                p.x = (unsigned)f2bf(v.x) | ((unsigned)f2bf(v.y) << 16);
                p.y = (unsigned)f2bf(v.z) | ((unsigned)f2bf(v.w) << 16);
                *(uint2*)(dst + 4 * q) = p;
            }
        }
        {
            unsigned short* dst = &Bs[row * 32 + half * 16];
            if (nrow < VOCAB){
                const float* srcp = Bbase + k0 + half * 16;
                #pragma unroll
                for (int q = 0; q < 4; ++q){
                    float4 v = *(const float4*)(srcp + 4 * q);
                    uint2 p;
                    p.x = (unsigned)f2bf(v.x) | ((unsigned)f2bf(v.y) << 16);
                    p.y = (unsigned)f2bf(v.z) | ((unsigned)f2bf(v.w) << 16);
                    *(uint2*)(dst + 4 * q) = p;
                }
            } else {
                uint2 zz; zz.x = 0u; zz.y = 0u;
                #pragma unroll
                for (int q = 0; q < 4; ++q) *(uint2*)(dst + 4 * q) = zz;
            }
        }
        __syncthreads();

        const unsigned short* Ab = &As[(wm * 64 + lr) * 32 + kq * 8];
        const unsigned short* Bb = &Bs[(wn * 64 + lr) * 32 + kq * 8];
        s16x8 af[4], bf[4];
        #pragma unroll
        for (int mf = 0; mf < 4; ++mf) af[mf] = *(const s16x8*)(Ab + mf * 16 * 32);
        #pragma unroll
        for (int nf = 0; nf < 4; ++nf) bf[nf] = *(const s16x8*)(Bb + nf * 16 * 32);
        #pragma unroll
        for (int mf = 0; mf < 4; ++mf){
            #pragma unroll
            for (int nf = 0; nf < 4; ++nf){
                acc[mf][nf] = __builtin_amdgcn_mfma_f32_16x16x32_bf16(af[mf], bf[nf], acc[mf][nf], 0, 0, 0);
            }
        }
        __syncthreads();
    }

    #pragma unroll
    for (int nf = 0; nf < 4; ++nf){
        const int n = ntile * 128 + wn * 64 + nf * 16 + lr;
        if (n >= VOCAB) continue;
        const float bp = b_pred[n];
        #pragma unroll
        for (int mf = 0; mf < 4; ++mf){
            const int m = mtile * 128 + wm * 64 + mf * 16 + kq * 4;
            #pragma unroll
            for (int q = 0; q < 4; ++q){
                out[(size_t)(m + q) * VOCAB + n] = acc[mf][nf][q] + bp;
            }
        }
    }
}

// ---------------------------------------------------------------------------
extern "C" void kernel_launch(void* const* d_in, const int* in_sizes, int n_in,
                              void* d_out, int out_size, void* d_ws, size_t ws_size,
                              hipStream_t stream){
    const float* x      = (const float*)d_in[0];
    const float* h0     = (const float*)d_in[1];
    const float* w_ih   = (const float*)d_in[2];
    const float* w_hh   = (const float*)d_in[3];
    const float* b_ih   = (const float*)d_in[4];
    const float* b_hh   = (const float*)d_in[5];
    const float* w_pred = (const float*)d_in[6];
    const float* b_pred = (const float*)d_in[7];
    float* out = (float*)d_out;

    float*    xg   = (float*)d_ws;                        // 1024*1536 fp32
    float*    hs   = xg + (size_t)T_STEPS * (3*HDIM);     // 1025*512  fp32
    unsigned* ctrl = (unsigned*)(hs + (size_t)(T_STEPS+1) * HDIM);  // 8 u32

    hipLaunchKernelGGL(init_hs_kernel, dim3(T_STEPS + 1), dim3(HDIM), 0, stream, h0, hs, ctrl);
    hipLaunchKernelGGL(xg_kernel,      dim3(6, 128),      dim3(256),  0, stream, x, w_ih, b_ih, xg);
    hipLaunchKernelGGL(scan_kernel,    dim3(256),         dim3(256),  0, stream, xg, w_hh, b_hh, hs, ctrl);
    hipLaunchKernelGGL(pred_gemm_kernel, dim3(8, 227),    dim3(256),  0, stream, hs, w_pred, b_pred, out);
}

// Round 4
// 3261.112 us; speedup vs baseline: 1.3039x; 1.3039x over previous
//
#include <hip/hip_runtime.h>
#include <hip/hip_bf16.h>
#include <cstdint>

#define VOCAB 28996
#define T_STEPS 1024
#define D_IN 256
#define HDIM 512

using f32x4 = __attribute__((ext_vector_type(4))) float;
using s16x8 = __attribute__((ext_vector_type(8))) short;

static __device__ __forceinline__ unsigned short f2bf(float f){
    unsigned u = __float_as_uint(f);
    u = u + 0x7FFFu + ((u >> 16) & 1u);   // round-to-nearest-even
    return (unsigned short)(u >> 16);
}

// ---------------------------------------------------------------------------
// Kernel 1: init — hs row 0 = h0; zero ctrl (8 rank counters + 8 padded flags)
// ---------------------------------------------------------------------------
__global__ void init_hs_kernel(const float* __restrict__ h0, float* __restrict__ hs,
                               unsigned* __restrict__ ctrl){
    const int tid = threadIdx.x;          // 0..511
    hs[tid] = h0[tid];
    if (tid < 288) ctrl[tid] = 0u;
}

// ---------------------------------------------------------------------------
// Kernel 2: xg = x @ w_ih^T + b_ih   ([1024 x 256] @ [256 -> 1536])  fp32
// ---------------------------------------------------------------------------
__global__ void xg_kernel(const float* __restrict__ x, const float* __restrict__ w_ih,
                          const float* __restrict__ b_ih, float* __restrict__ xg){
    __shared__ float xs[8][D_IN];
    const int tid = threadIdx.x;
    const int i   = blockIdx.x * 256 + tid;   // 0..1535
    const int t0  = blockIdx.y * 8;
    #pragma unroll
    for (int r = 0; r < 8; ++r)
        xs[r][tid] = x[(size_t)(t0 + r) * D_IN + tid];
    __syncthreads();

    float acc[8] = {0.f,0.f,0.f,0.f,0.f,0.f,0.f,0.f};
    const float* wrow = w_ih + (size_t)i * D_IN;
    for (int d = 0; d < D_IN; d += 4){
        float4 w4 = *(const float4*)(wrow + d);
        #pragma unroll
        for (int r = 0; r < 8; ++r){
            acc[r] += w4.x * xs[r][d]   + w4.y * xs[r][d+1]
                    + w4.z * xs[r][d+2] + w4.w * xs[r][d+3];
        }
    }
    const float b = b_ih[i];
    #pragma unroll
    for (int r = 0; r < 8; ++r)
        xg[(size_t)(t0 + r) * (3*HDIM) + i] = acc[r] + b;
}

// ---------------------------------------------------------------------------
// Kernel 3: GRU scan — per-XCD redundant clusters of 16 WGs x 512 threads.
// Sync protocol (all XCD-L2-local):
//   writers: plain stores -> per-wave s_waitcnt vmcnt(0) -> flag += 1 (wg-scope
//            atomic executes at this XCD's L2). 8 waves x 16 WGs = 128/step.
//   readers: ONE lane polls flag via atomic-add-of-opaque-zero (fresh L2 read),
//            then the WG plain-loads the 2KB row (L1 provably cold or merged:
//            each WG owns an exclusive 128B segment of every row).
// Incomplete clusters: bounded poll timeout + block-consensus exit. Complete
// cluster guaranteed by pigeonhole (128 WGs / 8 XCDs). All clusters write
// identical values -> cross-XCD dirty-line collisions are benign.
// ---------------------------------------------------------------------------
__launch_bounds__(512)
__global__ void scan_kernel(const float* __restrict__ xg, const float* __restrict__ w_hh,
                            const float* __restrict__ b_hh, float* hs, unsigned* ctrl){
    __shared__ __align__(16) float hbuf[HDIM];
    __shared__ unsigned sh_rank, sh_xcc;
    __shared__ int sh_go;

    const int tid = threadIdx.x;
    if (tid == 0){
        unsigned xcc;
        asm volatile("s_getreg_b32 %0, hwreg(HW_REG_XCC_ID)" : "=s"(xcc));
        xcc &= 7u;
        sh_xcc  = xcc;
        sh_rank = __hip_atomic_fetch_add(&ctrl[xcc], 1u, __ATOMIC_RELAXED,
                                         __HIP_MEMORY_SCOPE_AGENT);
        sh_go = 1;
    }
    __syncthreads();
    const unsigned rank = sh_rank;
    if (rank >= 16u) return;              // uniform per WG

    unsigned* flag = ctrl + 32 + sh_xcc * 32;   // own 128B line per XCD

    const int c  = tid & 15;              // column-chunk selector 0..15
    const int jl = tid >> 4;              // row-local 0..31
    const int j  = (int)rank * 32 + jl;   // 0..511

    // -- recurrent weights -> registers (96 VGPRs, fp32) --
    float4 WR[8], WZ[8], WN[8];
    const float* wr = w_hh + (size_t)j * HDIM;
    const float* wz = w_hh + (size_t)(HDIM   + j) * HDIM;
    const float* wn = w_hh + (size_t)(2*HDIM + j) * HDIM;
    #pragma unroll
    for (int s = 0; s < 8; ++s){
        const int off = 4 * (c + 16 * s);
        WR[s] = *(const float4*)(wr + off);
        WZ[s] = *(const float4*)(wz + off);
        WN[s] = *(const float4*)(wn + off);
    }
    float bhr = 0.f, bhz = 0.f, bhn = 0.f;
    if (c == 0){ bhr = b_hh[j]; bhz = b_hh[HDIM + j]; bhn = b_hh[2*HDIM + j]; }

    // opaque zero defeats InstCombine's fetch_add(p,0) -> load folding
    unsigned zero32 = 0u;
    asm volatile("" : "+v"(zero32));

    // xg software pipeline (distance 1)
    float xr_c = 0.f, xz_c = 0.f, xn_c = 0.f;
    if (c == 0){ xr_c = xg[j]; xz_c = xg[HDIM + j]; xn_c = xg[2*HDIM + j]; }

    #pragma unroll 1
    for (int t = 0; t < T_STEPS; ++t){
        // prefetch next step's xg (latency hides under poll + compute)
        float xr_n = 0.f, xz_n = 0.f, xn_n = 0.f;
        if (c == 0 && t + 1 < T_STEPS){
            const float* xgn = xg + (size_t)(t + 1) * (3*HDIM);
            xr_n = xgn[j]; xz_n = xgn[HDIM + j]; xn_n = xgn[2*HDIM + j];
        }

        // ---- wait for h_t publication (single-lane flag poll, L2-local) ----
        if (t > 0 && tid == 0){
            const int target = 128 * t;
            int spins = 0;
            for (;;){
                unsigned v = __hip_atomic_fetch_add(flag, zero32, __ATOMIC_RELAXED,
                                                    __HIP_MEMORY_SCOPE_WORKGROUP);
                if ((int)v >= target) break;
                if (++spins > 3000){ sh_go = 0; break; }  // incomplete cluster
            }
        }
        __syncthreads();
        if (!sh_go) return;               // uniform consensus exit

        // ---- load h_t row (plain, coalesced; L2-fresh per protocol) ----
        hbuf[tid] = hs[(size_t)t * HDIM + tid];
        __syncthreads();

        // ---- partial matvec: 96 FMAs/lane, 6 independent chains ----
        float ar0=0.f, ar1=0.f, az0=0.f, az1=0.f, an0=0.f, an1=0.f;
        #pragma unroll
        for (int s = 0; s < 8; s += 2){
            float4 h4 = *(const float4*)&hbuf[4 * (c + 16 * s)];
            ar0 += WR[s].x*h4.x + WR[s].y*h4.y + WR[s].z*h4.z + WR[s].w*h4.w;
            az0 += WZ[s].x*h4.x + WZ[s].y*h4.y + WZ[s].z*h4.z + WZ[s].w*h4.w;
            an0 += WN[s].x*h4.x + WN[s].y*h4.y + WN[s].z*h4.z + WN[s].w*h4.w;
            float4 h5 = *(const float4*)&hbuf[4 * (c + 16 * (s+1))];
            ar1 += WR[s+1].x*h5.x + WR[s+1].y*h5.y + WR[s+1].z*h5.z + WR[s+1].w*h5.w;
            az1 += WZ[s+1].x*h5.x + WZ[s+1].y*h5.y + WZ[s+1].z*h5.z + WZ[s+1].w*h5.w;
            an1 += WN[s+1].x*h5.x + WN[s+1].y*h5.y + WN[s+1].z*h5.z + WN[s+1].w*h5.w;
        }
        float ar = ar0 + ar1, az = az0 + az1, an = an0 + an1;
        #pragma unroll
        for (int m = 1; m < 16; m <<= 1){
            ar += __shfl_xor(ar, m);
            az += __shfl_xor(az, m);
            an += __shfl_xor(an, m);
        }

        if (c == 0){
            const float r  = 1.0f / (1.0f + __expf(-(xr_c + ar + bhr)));
            const float z  = 1.0f / (1.0f + __expf(-(xz_c + az + bhz)));
            const float nn = xn_c + r * (an + bhn);
            const float e  = __expf(2.0f * nn);
            const float th = 1.0f - 2.0f / (e + 1.0f);   // tanh, inf-safe
            const float hnew = (1.0f - z) * th + z * hbuf[j];
            hs[(size_t)(t + 1) * HDIM + j] = hnew;       // plain store
        }
        // publish: drain this wave's stores to L2, then one inc per wave
        asm volatile("s_waitcnt vmcnt(0)" ::: "memory");
        if ((tid & 63) == 0){
            __hip_atomic_fetch_add(flag, 1u, __ATOMIC_RELAXED,
                                   __HIP_MEMORY_SCOPE_WORKGROUP);
        }
        xr_c = xr_n; xz_c = xz_n; xn_c = xn_n;
    }
}

// ---------------------------------------------------------------------------
// Kernel 4: preds = hs[1..1024] @ w_pred^T + b_pred  (bf16 MFMA, fp32 out)
// ---------------------------------------------------------------------------
__launch_bounds__(256)
__global__ void pred_gemm_kernel(const float* __restrict__ hs, const float* __restrict__ w_pred,
                                 const float* __restrict__ b_pred, float* __restrict__ out){
    __shared__ unsigned short As[128 * 32];
    __shared__ unsigned short Bs[128 * 32];
    const int tid   = threadIdx.x;
    const int mtile = blockIdx.x;    // 0..7
    const int ntile = blockIdx.y;    // 0..226
    const int row  = tid >> 1, half = tid & 1;
    const int wave = tid >> 6, lane = tid & 63;
    const int wm = wave >> 1, wn = wave & 1;
    const int lr = lane & 15, kq = lane >> 4;

    f32x4 acc[4][4] = {};

    const float* Abase = hs + HDIM /*skip h0 row*/ + (size_t)(mtile * 128 + row) * HDIM;
    const int    nrow  = ntile * 128 + row;
    const float* Bbase = w_pred + (size_t)nrow * HDIM;

    for (int k0 = 0; k0 < HDIM; k0 += 32){
        {
            const float* srcp = Abase + k0 + half * 16;
            unsigned short* dst = &As[row * 32 + half * 16];
            #pragma unroll
            for (int q = 0; q < 4; ++q){
                float4 v = *(const float4*)(srcp + 4 * q);
                uint2 p;
                p.x = (unsigned)f2bf(v.x) | ((unsigned)f2bf(v.y) << 16);
                p.y = (unsigned)f2bf(v.z) | ((unsigned)f2bf(v.w) << 16);
                *(uint2*)(dst + 4 * q) = p;
            }
        }
        {
            unsigned short* dst = &Bs[row * 32 + half * 16];
            if (nrow < VOCAB){
                const float* srcp = Bbase + k0 + half * 16;
                #pragma unroll
                for (int q = 0; q < 4; ++q){
                    float4 v = *(const float4*)(srcp + 4 * q);
                    uint2 p;
                    p.x = (unsigned)f2bf(v.x) | ((unsigned)f2bf(v.y) << 16);
                    p.y = (unsigned)f2bf(v.z) | ((unsigned)f2bf(v.w) << 16);
                    *(uint2*)(dst + 4 * q) = p;
                }
            } else {
                uint2 zz; zz.x = 0u; zz.y = 0u;
                #pragma unroll
                for (int q = 0; q < 4; ++q) *(uint2*)(dst + 4 * q) = zz;
            }
        }
        __syncthreads();

        const unsigned short* Ab = &As[(wm * 64 + lr) * 32 + kq * 8];
        const unsigned short* Bb = &Bs[(wn * 64 + lr) * 32 + kq * 8];
        s16x8 af[4], bf[4];
        #pragma unroll
        for (int mf = 0; mf < 4; ++mf) af[mf] = *(const s16x8*)(Ab + mf * 16 * 32);
        #pragma unroll
        for (int nf = 0; nf < 4; ++nf) bf[nf] = *(const s16x8*)(Bb + nf * 16 * 32);
        #pragma unroll
        for (int mf = 0; mf < 4; ++mf){
            #pragma unroll
            for (int nf = 0; nf < 4; ++nf){
                acc[mf][nf] = __builtin_amdgcn_mfma_f32_16x16x32_bf16(af[mf], bf[nf], acc[mf][nf], 0, 0, 0);
            }
        }
        __syncthreads();
    }

    #pragma unroll
    for (int nf = 0; nf < 4; ++nf){
        const int n = ntile * 128 + wn * 64 + nf * 16 + lr;
        if (n >= VOCAB) continue;
        const float bp = b_pred[n];
        #pragma unroll
        for (int mf = 0; mf < 4; ++mf){
            const int m = mtile * 128 + wm * 64 + mf * 16 + kq * 4;
            #pragma unroll
            for (int q = 0; q < 4; ++q){
                out[(size_t)(m + q) * VOCAB + n] = acc[mf][nf][q] + bp;
            }
        }
    }
}

// ---------------------------------------------------------------------------
extern "C" void kernel_launch(void* const* d_in, const int* in_sizes, int n_in,
                              void* d_out, int out_size, void* d_ws, size_t ws_size,
                              hipStream_t stream){
    const float* x      = (const float*)d_in[0];
    const float* h0     = (const float*)d_in[1];
    const float* w_ih   = (const float*)d_in[2];
    const float* w_hh   = (const float*)d_in[3];
    const float* b_ih   = (const float*)d_in[4];
    const float* b_hh   = (const float*)d_in[5];
    const float* w_pred = (const float*)d_in[6];
    const float* b_pred = (const float*)d_in[7];
    float* out = (float*)d_out;

    float*    xg   = (float*)d_ws;                        // 1024*1536 fp32
    float*    hs   = xg + (size_t)T_STEPS * (3*HDIM);     // 1025*512  fp32
    unsigned* ctrl = (unsigned*)(hs + (size_t)(T_STEPS+1) * HDIM);  // 288 u32

    hipLaunchKernelGGL(init_hs_kernel, dim3(1),        dim3(HDIM), 0, stream, h0, hs, ctrl);
    hipLaunchKernelGGL(xg_kernel,      dim3(6, 128),   dim3(256),  0, stream, x, w_ih, b_ih, xg);
    hipLaunchKernelGGL(scan_kernel,    dim3(128),      dim3(512),  0, stream, xg, w_hh, b_hh, hs, ctrl);
    hipLaunchKernelGGL(pred_gemm_kernel, dim3(8, 227), dim3(256),  0, stream, hs, w_pred, b_pred, out);
}

// Round 5
// 2307.797 us; speedup vs baseline: 1.8425x; 1.4131x over previous
//
#include <hip/hip_runtime.h>
#include <hip/hip_bf16.h>
#include <cstdint>

#define VOCAB 28996
#define T_STEPS 1024
#define D_IN 256
#define HDIM 512

using f32x4 = __attribute__((ext_vector_type(4))) float;
using s16x8 = __attribute__((ext_vector_type(8))) short;

static __device__ __forceinline__ unsigned short f2bf(float f){
    unsigned u = __float_as_uint(f);
    u = u + 0x7FFFu + ((u >> 16) & 1u);   // round-to-nearest-even
    return (unsigned short)(u >> 16);
}

// ctrl layout (dwords): [0..7] per-XCD rank counters; [32 + xcc*512 + r*32] =
// slot for (XCD xcc, WG r) — each slot on its own 128B line. Total 4128 dwords.
#define CTRL_DWORDS 4128

// ---------------------------------------------------------------------------
// Kernel 1: init — hs row 0 = h0; zero all of ctrl (rank counters + slots)
// ---------------------------------------------------------------------------
__global__ void init_hs_kernel(const float* __restrict__ h0, float* __restrict__ hs,
                               unsigned* __restrict__ ctrl){
    const int tid = threadIdx.x;          // 0..1023
    if (tid < HDIM) hs[tid] = h0[tid];
    for (int i = tid; i < CTRL_DWORDS; i += 1024) ctrl[i] = 0u;
}

// ---------------------------------------------------------------------------
// Kernel 2: xg = x @ w_ih^T + b_ih   ([1024 x 256] @ [256 -> 1536])  fp32
// ---------------------------------------------------------------------------
__global__ void xg_kernel(const float* __restrict__ x, const float* __restrict__ w_ih,
                          const float* __restrict__ b_ih, float* __restrict__ xg){
    __shared__ float xs[8][D_IN];
    const int tid = threadIdx.x;
    const int i   = blockIdx.x * 256 + tid;   // 0..1535
    const int t0  = blockIdx.y * 8;
    #pragma unroll
    for (int r = 0; r < 8; ++r)
        xs[r][tid] = x[(size_t)(t0 + r) * D_IN + tid];
    __syncthreads();

    float acc[8] = {0.f,0.f,0.f,0.f,0.f,0.f,0.f,0.f};
    const float* wrow = w_ih + (size_t)i * D_IN;
    for (int d = 0; d < D_IN; d += 4){
        float4 w4 = *(const float4*)(wrow + d);
        #pragma unroll
        for (int r = 0; r < 8; ++r){
            acc[r] += w4.x * xs[r][d]   + w4.y * xs[r][d+1]
                    + w4.z * xs[r][d+2] + w4.w * xs[r][d+3];
        }
    }
    const float b = b_ih[i];
    #pragma unroll
    for (int r = 0; r < 8; ++r)
        xg[(size_t)(t0 + r) * (3*HDIM) + i] = acc[r] + b;
}

// ---------------------------------------------------------------------------
// Kernel 3: GRU scan — per-XCD redundant clusters, 16 WGs x 512 thr each.
// Sync (all XCD-L2-local, no __syncthreads in the loop):
//   publish: each wave: plain stores -> s_waitcnt vmcnt(0) -> fetch_add(+1) on
//            its WG's slot (slots on separate 128B lines; 8 incs/line/step).
//   detect:  wave 0, lanes 0..15 RMW-poll (add-0) the 16 slots in parallel
//            (s_sleep backoff), relay via LDS sh_step; waves 1..7 ds-spin.
//   stage:   per-wave private LDS row copy (no cross-wave deps).
// Incomplete clusters: bounded timeout -> sh_step=INT_MAX -> uniform exit.
// All clusters write identical hs values; >=1 complete cluster by pigeonhole.
// ---------------------------------------------------------------------------
__launch_bounds__(512, 1)
__global__ void scan_kernel(const float* __restrict__ xg, const float* __restrict__ w_hh,
                            const float* __restrict__ b_hh, float* hs, unsigned* ctrl){
    __shared__ __align__(16) float hbuf[8][HDIM];   // per-wave row copies (16KB)
    __shared__ unsigned sh_rank, sh_xcc;
    __shared__ int sh_step;

    const int tid = threadIdx.x;
    if (tid == 0){
        unsigned xcc;
        asm volatile("s_getreg_b32 %0, hwreg(HW_REG_XCC_ID)" : "=s"(xcc));
        xcc &= 7u;
        sh_xcc  = xcc;
        sh_rank = __hip_atomic_fetch_add(&ctrl[xcc], 1u, __ATOMIC_RELAXED,
                                         __HIP_MEMORY_SCOPE_AGENT);
        sh_step = 0;
    }
    __syncthreads();
    const unsigned rank = sh_rank;
    if (rank >= 16u) return;              // uniform per WG

    unsigned* slots  = ctrl + 32 + sh_xcc * 512;    // 16 slots, 128B apart
    unsigned* myslot = slots + rank * 32;

    const int wv   = tid >> 6;            // wave 0..7
    const int lane = tid & 63;
    const int c    = tid & 15;            // column-chunk selector 0..15
    const int jl   = tid >> 4;            // 0..31
    const int j    = (int)rank * 32 + jl; // 0..511

    // -- recurrent weights -> registers (96 VGPRs, fp32) --
    float4 WR[8], WZ[8], WN[8];
    const float* wr = w_hh + (size_t)j * HDIM;
    const float* wz = w_hh + (size_t)(HDIM   + j) * HDIM;
    const float* wn = w_hh + (size_t)(2*HDIM + j) * HDIM;
    #pragma unroll
    for (int s = 0; s < 8; ++s){
        const int off = 4 * (c + 16 * s);
        WR[s] = *(const float4*)(wr + off);
        WZ[s] = *(const float4*)(wz + off);
        WN[s] = *(const float4*)(wn + off);
    }
    float bhr = 0.f, bhz = 0.f, bhn = 0.f;
    if (c == 0){ bhr = b_hh[j]; bhz = b_hh[HDIM + j]; bhn = b_hh[2*HDIM + j]; }

    // opaque zero defeats InstCombine's fetch_add(p,0) -> load folding
    unsigned zero32 = 0u;
    asm volatile("" : "+v"(zero32));

    // xg software pipeline (distance 1)
    float xr_c = 0.f, xz_c = 0.f, xn_c = 0.f;
    if (c == 0){ xr_c = xg[j]; xz_c = xg[HDIM + j]; xn_c = xg[2*HDIM + j]; }

    #pragma unroll 1
    for (int t = 0; t < T_STEPS; ++t){
        // prefetch next step's xg (completes long before next publish vmcnt)
        float xr_n = 0.f, xz_n = 0.f, xn_n = 0.f;
        if (c == 0 && t + 1 < T_STEPS){
            const float* xgn = xg + (size_t)(t + 1) * (3*HDIM);
            xr_n = xgn[j]; xz_n = xgn[HDIM + j]; xn_n = xgn[2*HDIM + j];
        }

        // ---- detect h_t ready ----
        if (t > 0){
            if (wv == 0){
                int fail = 0;
                if (lane < 16){
                    const unsigned tgt = 8u * (unsigned)t;
                    int spins = 0;
                    for (;;){
                        unsigned v = __hip_atomic_fetch_add(slots + lane * 32, zero32,
                                        __ATOMIC_RELAXED, __HIP_MEMORY_SCOPE_WORKGROUP);
                        if (v >= tgt) break;
                        if (++spins > 8000){ fail = 1; break; }
                        __builtin_amdgcn_s_sleep(1);
                    }
                }
                if (__any(fail)){
                    if (lane == 0)
                        __hip_atomic_store(&sh_step, 0x7FFFFFFF, __ATOMIC_RELAXED,
                                           __HIP_MEMORY_SCOPE_WORKGROUP);
                    return;
                }
                if (lane == 0)
                    __hip_atomic_store(&sh_step, t, __ATOMIC_RELAXED,
                                       __HIP_MEMORY_SCOPE_WORKGROUP);
            } else {
                int v;
                do {
                    v = __hip_atomic_load(&sh_step, __ATOMIC_RELAXED,
                                          __HIP_MEMORY_SCOPE_WORKGROUP);
                } while (v < t);
                if (v == 0x7FFFFFFF) return;
            }
        }

        // ---- stage h_t row per-wave (plain loads; L2-fresh per protocol) ----
        {
            const float* rowp = hs + (size_t)t * HDIM + 8 * lane;
            float4 va = *(const float4*)(rowp);
            float4 vb = *(const float4*)(rowp + 4);
            *(float4*)&hbuf[wv][8 * lane]     = va;
            *(float4*)&hbuf[wv][8 * lane + 4] = vb;
        }

        // ---- partial matvec: 96 FMAs/lane, 6 independent chains ----
        float ar0=0.f, ar1=0.f, az0=0.f, az1=0.f, an0=0.f, an1=0.f;
        #pragma unroll
        for (int s = 0; s < 8; s += 2){
            float4 h4 = *(const float4*)&hbuf[wv][4 * (c + 16 * s)];
            ar0 += WR[s].x*h4.x + WR[s].y*h4.y + WR[s].z*h4.z + WR[s].w*h4.w;
            az0 += WZ[s].x*h4.x + WZ[s].y*h4.y + WZ[s].z*h4.z + WZ[s].w*h4.w;
            an0 += WN[s].x*h4.x + WN[s].y*h4.y + WN[s].z*h4.z + WN[s].w*h4.w;
            float4 h5 = *(const float4*)&hbuf[wv][4 * (c + 16 * (s+1))];
            ar1 += WR[s+1].x*h5.x + WR[s+1].y*h5.y + WR[s+1].z*h5.z + WR[s+1].w*h5.w;
            az1 += WZ[s+1].x*h5.x + WZ[s+1].y*h5.y + WZ[s+1].z*h5.z + WZ[s+1].w*h5.w;
            an1 += WN[s+1].x*h5.x + WN[s+1].y*h5.y + WN[s+1].z*h5.z + WN[s+1].w*h5.w;
        }
        float ar = ar0 + ar1, az = az0 + az1, an = an0 + an1;
        #pragma unroll
        for (int m = 1; m < 16; m <<= 1){
            ar += __shfl_xor(ar, m);
            az += __shfl_xor(az, m);
            an += __shfl_xor(an, m);
        }

        if (c == 0){
            const float r  = 1.0f / (1.0f + __expf(-(xr_c + ar + bhr)));
            const float z  = 1.0f / (1.0f + __expf(-(xz_c + az + bhz)));
            const float nn = xn_c + r * (an + bhn);
            const float e  = __expf(2.0f * nn);
            const float th = 1.0f - 2.0f / (e + 1.0f);   // tanh, inf-safe
            const float hnew = (1.0f - z) * th + z * hbuf[wv][j];
            hs[(size_t)(t + 1) * HDIM + j] = hnew;       // plain store
        }
        // publish: drain THIS wave's stores to L2, then one inc on own slot
        asm volatile("s_waitcnt vmcnt(0)" ::: "memory");
        if (lane == 0){
            __hip_atomic_fetch_add(myslot, 1u, __ATOMIC_RELAXED,
                                   __HIP_MEMORY_SCOPE_WORKGROUP);
        }
        xr_c = xr_n; xz_c = xz_n; xn_c = xn_n;
    }
}

// ---------------------------------------------------------------------------
// Kernel 4: preds = hs[1..1024] @ w_pred^T + b_pred  (bf16 MFMA, fp32 out)
// ---------------------------------------------------------------------------
__launch_bounds__(256)
__global__ void pred_gemm_kernel(const float* __restrict__ hs, const float* __restrict__ w_pred,
                                 const float* __restrict__ b_pred, float* __restrict__ out){
    __shared__ unsigned short As[128 * 32];
    __shared__ unsigned short Bs[128 * 32];
    const int tid   = threadIdx.x;
    const int mtile = blockIdx.x;    // 0..7
    const int ntile = blockIdx.y;    // 0..226
    const int row  = tid >> 1, half = tid & 1;
    const int wave = tid >> 6, lane = tid & 63;
    const int wm = wave >> 1, wn = wave & 1;
    const int lr = lane & 15, kq = lane >> 4;

    f32x4 acc[4][4] = {};

    const float* Abase = hs + HDIM /*skip h0 row*/ + (size_t)(mtile * 128 + row) * HDIM;
    const int    nrow  = ntile * 128 + row;
    const float* Bbase = w_pred + (size_t)nrow * HDIM;

    for (int k0 = 0; k0 < HDIM; k0 += 32){
        {
            const float* srcp = Abase + k0 + half * 16;
            unsigned short* dst = &As[row * 32 + half * 16];
            #pragma unroll
            for (int q = 0; q < 4; ++q){
                float4 v = *(const float4*)(srcp + 4 * q);
                uint2 p;
                p.x = (unsigned)f2bf(v.x) | ((unsigned)f2bf(v.y) << 16);
                p.y = (unsigned)f2bf(v.z) | ((unsigned)f2bf(v.w) << 16);
                *(uint2*)(dst + 4 * q) = p;
            }
        }
        {
            unsigned short* dst = &Bs[row * 32 + half * 16];
            if (nrow < VOCAB){
                const float* srcp = Bbase + k0 + half * 16;
                #pragma unroll
                for (int q = 0; q < 4; ++q){
                    float4 v = *(const float4*)(srcp + 4 * q);
                    uint2 p;
                    p.x = (unsigned)f2bf(v.x) | ((unsigned)f2bf(v.y) << 16);
                    p.y = (unsigned)f2bf(v.z) | ((unsigned)f2bf(v.w) << 16);
                    *(uint2*)(dst + 4 * q) = p;
                }
            } else {
                uint2 zz; zz.x = 0u; zz.y = 0u;
                #pragma unroll
                for (int q = 0; q < 4; ++q) *(uint2*)(dst + 4 * q) = zz;
            }
        }
        __syncthreads();

        const unsigned short* Ab = &As[(wm * 64 + lr) * 32 + kq * 8];
        const unsigned short* Bb = &Bs[(wn * 64 + lr) * 32 + kq * 8];
        s16x8 af[4], bf[4];
        #pragma unroll
        for (int mf = 0; mf < 4; ++mf) af[mf] = *(const s16x8*)(Ab + mf * 16 * 32);
        #pragma unroll
        for (int nf = 0; nf < 4; ++nf) bf[nf] = *(const s16x8*)(Bb + nf * 16 * 32);
        #pragma unroll
        for (int mf = 0; mf < 4; ++mf){
            #pragma unroll
            for (int nf = 0; nf < 4; ++nf){
                acc[mf][nf] = __builtin_amdgcn_mfma_f32_16x16x32_bf16(af[mf], bf[nf], acc[mf][nf], 0, 0, 0);
            }
        }
        __syncthreads();
    }

    #pragma unroll
    for (int nf = 0; nf < 4; ++nf){
        const int n = ntile * 128 + wn * 64 + nf * 16 + lr;
        if (n >= VOCAB) continue;
        const float bp = b_pred[n];
        #pragma unroll
        for (int mf = 0; mf < 4; ++mf){
            const int m = mtile * 128 + wm * 64 + mf * 16 + kq * 4;
            #pragma unroll
            for (int q = 0; q < 4; ++q){
                out[(size_t)(m + q) * VOCAB + n] = acc[mf][nf][q] + bp;
            }
        }
    }
}

// ---------------------------------------------------------------------------
extern "C" void kernel_launch(void* const* d_in, const int* in_sizes, int n_in,
                              void* d_out, int out_size, void* d_ws, size_t ws_size,
                              hipStream_t stream){
    const float* x      = (const float*)d_in[0];
    const float* h0     = (const float*)d_in[1];
    const float* w_ih   = (const float*)d_in[2];
    const float* w_hh   = (const float*)d_in[3];
    const float* b_ih   = (const float*)d_in[4];
    const float* b_hh   = (const float*)d_in[5];
    const float* w_pred = (const float*)d_in[6];
    const float* b_pred = (const float*)d_in[7];
    float* out = (float*)d_out;

    float*    xg   = (float*)d_ws;                        // 1024*1536 fp32
    float*    hs   = xg + (size_t)T_STEPS * (3*HDIM);     // 1025*512  fp32
    unsigned* ctrl = (unsigned*)(hs + (size_t)(T_STEPS+1) * HDIM);  // 4128 u32

    hipLaunchKernelGGL(init_hs_kernel, dim3(1),        dim3(1024), 0, stream, h0, hs, ctrl);
    hipLaunchKernelGGL(xg_kernel,      dim3(6, 128),   dim3(256),  0, stream, x, w_ih, b_ih, xg);
    hipLaunchKernelGGL(scan_kernel,    dim3(128),      dim3(512),  0, stream, xg, w_hh, b_hh, hs, ctrl);
    hipLaunchKernelGGL(pred_gemm_kernel, dim3(8, 227), dim3(256),  0, stream, hs, w_pred, b_pred, out);
}

// Round 8
// 1774.587 us; speedup vs baseline: 2.3961x; 1.3005x over previous
//
#include <hip/hip_runtime.h>
#include <hip/hip_bf16.h>
#include <cstdint>

#define VOCAB 28996
#define T_STEPS 1024
#define D_IN 256
#define HDIM 512

using f32x4 = __attribute__((ext_vector_type(4))) float;
using s16x8 = __attribute__((ext_vector_type(8))) short;

static __device__ __forceinline__ unsigned short f2bf(float f){
    unsigned u = __float_as_uint(f);
    u = u + 0x7FFFu + ((u >> 16) & 1u);   // round-to-nearest-even
    return (unsigned short)(u >> 16);
}

#define SENT_U 0x7FC00001u

// ---------------------------------------------------------------------------
// Kernel 1: init — hs row 0 = h0, rows 1..1024 = NaN sentinel; zero rank ctrs
// (re-runs every graph replay: sentinels are consumed by each scan pass)
// ---------------------------------------------------------------------------
__global__ void init_hs_kernel(const float* __restrict__ h0, float* __restrict__ hs,
                               unsigned* __restrict__ ctrl){
    const int col = threadIdx.x;          // 0..511
    const int row = blockIdx.x;           // 0..1024
    float v = (row == 0) ? h0[col] : __uint_as_float(SENT_U);
    hs[(size_t)row * HDIM + col] = v;
    if (row == 0 && col < 8) ctrl[col] = 0u;
}

// ---------------------------------------------------------------------------
// Kernel 2: xg = x @ w_ih^T + b_ih   ([1024 x 256] @ [256 -> 1536])  fp32
// ---------------------------------------------------------------------------
__global__ void xg_kernel(const float* __restrict__ x, const float* __restrict__ w_ih,
                          const float* __restrict__ b_ih, float* __restrict__ xg){
    __shared__ float xs[8][D_IN];
    const int tid = threadIdx.x;
    const int i   = blockIdx.x * 256 + tid;   // 0..1535
    const int t0  = blockIdx.y * 8;
    #pragma unroll
    for (int r = 0; r < 8; ++r)
        xs[r][tid] = x[(size_t)(t0 + r) * D_IN + tid];
    __syncthreads();

    float acc[8] = {0.f,0.f,0.f,0.f,0.f,0.f,0.f,0.f};
    const float* wrow = w_ih + (size_t)i * D_IN;
    for (int d = 0; d < D_IN; d += 4){
        float4 w4 = *(const float4*)(wrow + d);
        #pragma unroll
        for (int r = 0; r < 8; ++r){
            acc[r] += w4.x * xs[r][d]   + w4.y * xs[r][d+1]
                    + w4.z * xs[r][d+2] + w4.w * xs[r][d+3];
        }
    }
    const float b = b_ih[i];
    #pragma unroll
    for (int r = 0; r < 8; ++r)
        xg[(size_t)(t0 + r) * (3*HDIM) + i] = acc[r] + b;
}

// ---------------------------------------------------------------------------
// Kernel 3: GRU scan — per-XCD redundant clusters, 16 WGs x 512 thr.
// Data-as-flag with NT loads; ZERO atomics/flags/barriers/waitcnts in loop:
//   publish: plain stores (write-through, no-allocate -> land in XCD L2).
//   detect:  poll row t with `global_load_dwordx4 ... nt` — nt loads bypass /
//            never allocate L1, and hs lines are touched ONLY by nt loads and
//            write-through stores inside this kernel (kernel-start acquire
//            invalidated L1) -> every poll is a fresh XCD-L2 read. The r7
//            failure mode (sentinel stuck in reader L1) is impossible.
//   weights: 96 fp32/thread in VGPRs — loaded all at once, then pinned with
//            scalar "+v" asm ties (r5's VGPR=84 proved unpinned weights get
//            demoted to per-step L2 reloads = 3MB/step/XCD).
// Incomplete clusters (uneven dispatch): wave-uniform 5000-spin timeout ->
// return; runs concurrent with the live cluster. >=1 complete cluster by
// pigeonhole; all clusters write identical bytes so races are benign.
// ---------------------------------------------------------------------------
#define LDW(G, P, n) \
    float G##n##0 = (P)[64*n + 0], G##n##1 = (P)[64*n + 1], \
          G##n##2 = (P)[64*n + 2], G##n##3 = (P)[64*n + 3];
#define PINW(G, n) \
    asm volatile("" : "+v"(G##n##0), "+v"(G##n##1), "+v"(G##n##2), "+v"(G##n##3));

#define GSTEP(n, arx, azx, anx) { \
    float4 h4 = *(const float4*)&hbuf[wv][4*c + 64*n]; \
    arx += R##n##0*h4.x + R##n##1*h4.y + R##n##2*h4.z + R##n##3*h4.w; \
    azx += Z##n##0*h4.x + Z##n##1*h4.y + Z##n##2*h4.z + Z##n##3*h4.w; \
    anx += N##n##0*h4.x + N##n##1*h4.y + N##n##2*h4.z + N##n##3*h4.w; }

__launch_bounds__(512, 1)
__global__ void scan_kernel(const float* __restrict__ xg, const float* __restrict__ w_hh,
                            const float* __restrict__ b_hh, float* hs, unsigned* ctrl){
    __shared__ __align__(16) float hbuf[8][HDIM];   // per-wave private row copy
    __shared__ unsigned sh_rank;

    const int tid = threadIdx.x;
    if (tid == 0){
        unsigned xcc;
        asm volatile("s_getreg_b32 %0, hwreg(HW_REG_XCC_ID)" : "=s"(xcc));
        sh_rank = __hip_atomic_fetch_add(&ctrl[xcc & 7u], 1u, __ATOMIC_RELAXED,
                                         __HIP_MEMORY_SCOPE_AGENT);
    }
    __syncthreads();
    const unsigned rank = sh_rank;
    if (rank >= 16u) return;              // uniform per WG

    const int wv   = tid >> 6;            // wave 0..7
    const int lane = tid & 63;
    const int c    = tid & 15;            // column-chunk selector 0..15
    const int jl   = tid >> 4;            // 0..31
    const int j    = (int)rank * 32 + jl; // 0..511

    // -- recurrent weights: issue all 24 vector loads, then pin all 96 scalars
    const float* wrp = w_hh + (size_t)j * HDIM + 4*c;
    const float* wzp = w_hh + (size_t)(HDIM   + j) * HDIM + 4*c;
    const float* wnp = w_hh + (size_t)(2*HDIM + j) * HDIM + 4*c;
    LDW(R, wrp, 0) LDW(R, wrp, 1) LDW(R, wrp, 2) LDW(R, wrp, 3)
    LDW(R, wrp, 4) LDW(R, wrp, 5) LDW(R, wrp, 6) LDW(R, wrp, 7)
    LDW(Z, wzp, 0) LDW(Z, wzp, 1) LDW(Z, wzp, 2) LDW(Z, wzp, 3)
    LDW(Z, wzp, 4) LDW(Z, wzp, 5) LDW(Z, wzp, 6) LDW(Z, wzp, 7)
    LDW(N, wnp, 0) LDW(N, wnp, 1) LDW(N, wnp, 2) LDW(N, wnp, 3)
    LDW(N, wnp, 4) LDW(N, wnp, 5) LDW(N, wnp, 6) LDW(N, wnp, 7)
    PINW(R,0) PINW(R,1) PINW(R,2) PINW(R,3) PINW(R,4) PINW(R,5) PINW(R,6) PINW(R,7)
    PINW(Z,0) PINW(Z,1) PINW(Z,2) PINW(Z,3) PINW(Z,4) PINW(Z,5) PINW(Z,6) PINW(Z,7)
    PINW(N,0) PINW(N,1) PINW(N,2) PINW(N,3) PINW(N,4) PINW(N,5) PINW(N,6) PINW(N,7)

    float bhr = b_hh[j], bhz = b_hh[HDIM + j], bhn = b_hh[2*HDIM + j];
    asm volatile("" : "+v"(bhr), "+v"(bhz), "+v"(bhn));

    // xg pipeline register (filled for t=0 here, re-filled post-poll each step)
    float xr_c = 0.f, xz_c = 0.f, xn_c = 0.f;
    if (c == 0){ xr_c = xg[j]; xz_c = xg[HDIM + j]; xn_c = xg[2*HDIM + j]; }

    #pragma unroll 1
    for (int t = 0; t < T_STEPS; ++t){
        // ---- detect h_t ready: NT-poll the row itself (detect == stage) ----
        const float4* myp = (const float4*)(hs + (size_t)t * HDIM) + lane;
        float4 va, vb;
        int spins = 0;
        for (;;){
            asm volatile("global_load_dwordx4 %0, %2, off nt\n\t"
                         "global_load_dwordx4 %1, %2, off offset:1024 nt\n\t"
                         "s_waitcnt vmcnt(0)"
                         : "=&v"(va), "=&v"(vb) : "v"(myp) : "memory");
            int ok = (__float_as_uint(va.x) != SENT_U) & (__float_as_uint(va.y) != SENT_U)
                   & (__float_as_uint(va.z) != SENT_U) & (__float_as_uint(va.w) != SENT_U)
                   & (__float_as_uint(vb.x) != SENT_U) & (__float_as_uint(vb.y) != SENT_U)
                   & (__float_as_uint(vb.z) != SENT_U) & (__float_as_uint(vb.w) != SENT_U);
            if (__all(ok)) break;         // wave-uniform
            if (++spins > 5000) return;   // wave-uniform timeout (dead cluster)
        }

        // ---- prefetch next step's xg AFTER poll (hides under compute) ----
        float xr_n = 0.f, xz_n = 0.f, xn_n = 0.f;
        if (c == 0 && t + 1 < T_STEPS){
            const float* xgn = xg + (size_t)(t + 1) * (3*HDIM);
            xr_n = xgn[j]; xz_n = xgn[HDIM + j]; xn_n = xgn[2*HDIM + j];
        }

        // ---- stage to this wave's LDS row (contiguous 16B/lane) ----
        *(float4*)&hbuf[wv][4 * lane]       = va;
        *(float4*)&hbuf[wv][256 + 4 * lane] = vb;
        asm volatile("s_waitcnt lgkmcnt(0)" ::: "memory");
        __builtin_amdgcn_sched_barrier(0);

        // ---- partial matvec: 96 FMAs/lane, 6 independent chains ----
        float ar0=0.f, ar1=0.f, az0=0.f, az1=0.f, an0=0.f, an1=0.f;
        GSTEP(0, ar0, az0, an0)  GSTEP(1, ar1, az1, an1)
        GSTEP(2, ar0, az0, an0)  GSTEP(3, ar1, az1, an1)
        GSTEP(4, ar0, az0, an0)  GSTEP(5, ar1, az1, an1)
        GSTEP(6, ar0, az0, an0)  GSTEP(7, ar1, az1, an1)
        float ar = ar0 + ar1, az = az0 + az1, an = an0 + an1;
        #pragma unroll
        for (int m = 1; m < 16; m <<= 1){
            ar += __shfl_xor(ar, m);
            az += __shfl_xor(az, m);
            an += __shfl_xor(an, m);
        }

        if (c == 0){
            const float r  = 1.0f / (1.0f + __expf(-(xr_c + ar + bhr)));
            const float z  = 1.0f / (1.0f + __expf(-(xz_c + az + bhz)));
            const float nn = xn_c + r * (an + bhn);
            const float e  = __expf(2.0f * nn);
            const float th = 1.0f - 2.0f / (e + 1.0f);   // tanh, inf-safe
            const float hnew = (1.0f - z) * th + z * hbuf[wv][j];
            hs[(size_t)(t + 1) * HDIM + j] = hnew;   // plain store IS the flag
        }
        xr_c = xr_n; xz_c = xz_n; xn_c = xn_n;
    }
}

// ---------------------------------------------------------------------------
// Kernel 4: preds = hs[1..1024] @ w_pred^T + b_pred  (bf16 MFMA, fp32 out)
// ---------------------------------------------------------------------------
__launch_bounds__(256)
__global__ void pred_gemm_kernel(const float* __restrict__ hs, const float* __restrict__ w_pred,
                                 const float* __restrict__ b_pred, float* __restrict__ out){
    __shared__ unsigned short As[128 * 32];
    __shared__ unsigned short Bs[128 * 32];
    const int tid   = threadIdx.x;
    const int mtile = blockIdx.x;    // 0..7
    const int ntile = blockIdx.y;    // 0..226
    const int row  = tid >> 1, half = tid & 1;
    const int wave = tid >> 6, lane = tid & 63;
    const int wm = wave >> 1, wn = wave & 1;
    const int lr = lane & 15, kq = lane >> 4;

    f32x4 acc[4][4] = {};

    const float* Abase = hs + HDIM /*skip h0 row*/ + (size_t)(mtile * 128 + row) * HDIM;
    const int    nrow  = ntile * 128 + row;
    const float* Bbase = w_pred + (size_t)nrow * HDIM;

    for (int k0 = 0; k0 < HDIM; k0 += 32){
        {
            const float* srcp = Abase + k0 + half * 16;
            unsigned short* dst = &As[row * 32 + half * 16];
            #pragma unroll
            for (int q = 0; q < 4; ++q){
                float4 v = *(const float4*)(srcp + 4 * q);
                uint2 p;
                p.x = (unsigned)f2bf(v.x) | ((unsigned)f2bf(v.y) << 16);
                p.y = (unsigned)f2bf(v.z) | ((unsigned)f2bf(v.w) << 16);
                *(uint2*)(dst + 4 * q) = p;
            }
        }
        {
            unsigned short* dst = &Bs[row * 32 + half * 16];
            if (nrow < VOCAB){
                const float* srcp = Bbase + k0 + half * 16;
                #pragma unroll
                for (int q = 0; q < 4; ++q){
                    float4 v = *(const float4*)(srcp + 4 * q);
                    uint2 p;
                    p.x = (unsigned)f2bf(v.x) | ((unsigned)f2bf(v.y) << 16);
                    p.y = (unsigned)f2bf(v.z) | ((unsigned)f2bf(v.w) << 16);
                    *(uint2*)(dst + 4 * q) = p;
                }
            } else {
                uint2 zz; zz.x = 0u; zz.y = 0u;
                #pragma unroll
                for (int q = 0; q < 4; ++q) *(uint2*)(dst + 4 * q) = zz;
            }
        }
        __syncthreads();

        const unsigned short* Ab = &As[(wm * 64 + lr) * 32 + kq * 8];
        const unsigned short* Bb = &Bs[(wn * 64 + lr) * 32 + kq * 8];
        s16x8 af[4], bf[4];
        #pragma unroll
        for (int mf = 0; mf < 4; ++mf) af[mf] = *(const s16x8*)(Ab + mf * 16 * 32);
        #pragma unroll
        for (int nf = 0; nf < 4; ++nf) bf[nf] = *(const s16x8*)(Bb + nf * 16 * 32);
        #pragma unroll
        for (int mf = 0; mf < 4; ++mf){
            #pragma unroll
            for (int nf = 0; nf < 4; ++nf){
                acc[mf][nf] = __builtin_amdgcn_mfma_f32_16x16x32_bf16(af[mf], bf[nf], acc[mf][nf], 0, 0, 0);
            }
        }
        __syncthreads();
    }

    #pragma unroll
    for (int nf = 0; nf < 4; ++nf){
        const int n = ntile * 128 + wn * 64 + nf * 16 + lr;
        if (n >= VOCAB) continue;
        const float bp = b_pred[n];
        #pragma unroll
        for (int mf = 0; mf < 4; ++mf){
            const int m = mtile * 128 + wm * 64 + mf * 16 + kq * 4;
            #pragma unroll
            for (int q = 0; q < 4; ++q){
                out[(size_t)(m + q) * VOCAB + n] = acc[mf][nf][q] + bp;
            }
        }
    }
}

// ---------------------------------------------------------------------------
extern "C" void kernel_launch(void* const* d_in, const int* in_sizes, int n_in,
                              void* d_out, int out_size, void* d_ws, size_t ws_size,
                              hipStream_t stream){
    const float* x      = (const float*)d_in[0];
    const float* h0     = (const float*)d_in[1];
    const float* w_ih   = (const float*)d_in[2];
    const float* w_hh   = (const float*)d_in[3];
    const float* b_ih   = (const float*)d_in[4];
    const float* b_hh   = (const float*)d_in[5];
    const float* w_pred = (const float*)d_in[6];
    const float* b_pred = (const float*)d_in[7];
    float* out = (float*)d_out;

    float*    xg   = (float*)d_ws;                        // 1024*1536 fp32
    float*    hs   = xg + (size_t)T_STEPS * (3*HDIM);     // 1025*512  fp32
    unsigned* ctrl = (unsigned*)(hs + (size_t)(T_STEPS+1) * HDIM);  // 8 u32

    hipLaunchKernelGGL(init_hs_kernel, dim3(T_STEPS + 1), dim3(HDIM), 0, stream, h0, hs, ctrl);
    hipLaunchKernelGGL(xg_kernel,      dim3(6, 128),      dim3(256),  0, stream, x, w_ih, b_ih, xg);
    hipLaunchKernelGGL(scan_kernel,    dim3(128),         dim3(512),  0, stream, xg, w_hh, b_hh, hs, ctrl);
    hipLaunchKernelGGL(pred_gemm_kernel, dim3(8, 227),    dim3(256),  0, stream, hs, w_pred, b_pred, out);
}